// Round 8
// baseline (46712.354 us; speedup 1.0000x reference)
//
#include <hip/hip_runtime.h>
#include <hip/hip_bf16.h>

// ---------------------------------------------------------------------------
// RecurrentCellsModel: emb lookup -> GRU scan -> LSTM scan -> linear head.
// B=128, T=2048, D=256, H=512, O=6. Float tensors f32, tokens int32.
// No fp32 MFMA on CDNA4 -> hi+lo bf16 split (~2^-17 rel err).
//
// R7 post-mortem: 156->45ms from fence hygiene; counters scaled uniformly
// (MfmaUtil 2->5%, VALU 2->5%) => still serialized L2 maintenance: 32 wbl2 +
// 32 inv per XCD per step ~= 30us/step. R8 removes ALL per-step maintenance:
//   - consumers read h-exchange via relaxed AGENT 8B atomic loads (sc1 ->
//     LLC-coherent, bypass L1/L2, normal vmcnt pipelining by the compiler);
//   - release add RELAXED (barrier already drained write-through stores);
//     acquire fence deleted;
//   - ws counters zeroed by a write-through init kernel (no cached ws lines);
//   - head reads h_final via 8B atomic loads.
// Coherence argument: every access to ws exchange data is sc1/write-through
// (stores) or sc1 (loads); LLC is the single coherence point; kernel-boundary
// AQL acquire/release covers pre-kernel memset dirt; boot add keeps RELEASE
// (one wbl2/WG, once) as belt-and-braces.
//
// Persistent pipeline: 256 WGs x 256 thr, <=132KB dyn LDS => 1 WG/CU.
// WGs [0,128): GRU, [128,256): LSTM; 2 batch-groups(64 rows) x 64
// col-groups(8 cols) each. Weights LDS-resident as hi/lo planes; MFMA N-tile
// packs two gates; lane pair (L, L^8) swaps via __shfl_xor(8). fp32 state in
// registers. GRU -> 2-slot ring, LSTM -> 2-parity buffer in ws; per-bg
// arrive counters + relaxed polls.
//
// MFMA 16x16x32 bf16 layouts (HW-verified m89/m91/m120):
//   A: a[j]=A[m=lane&15][k=(lane>>4)*8+j]; B: b[j]=B[k=(lane>>4)*8+j][n=lane&15];
//   D: d[reg]=D[row=(lane>>4)*4+reg][col=lane&15].
//
// Fingerprints: 12345 = ws too small; ~1e4 = boot timeout; ~1e2 = stall.
// ---------------------------------------------------------------------------

typedef short v8s __attribute__((ext_vector_type(8)));
typedef float v4f __attribute__((ext_vector_type(4)));
typedef unsigned long long u64;

#define T_STEPS 2048
#define RING_OFF 8192
#define DYN_LDS 135168

#define MFMA16(a, b, c) __builtin_amdgcn_mfma_f32_16x16x32_bf16((a), (b), (c), 0, 0, 0)

__device__ __forceinline__ v4f v4zero() { v4f z = {0.f, 0.f, 0.f, 0.f}; return z; }
__device__ __forceinline__ float sigf(float x) { return 1.f / (1.f + __expf(-x)); }
__device__ __forceinline__ float tanhf_fast(float x) { return 1.f - 2.f / (1.f + __expf(2.f * x)); }

__device__ __forceinline__ ushort f2us(float v) {
  __hip_bfloat16 b = __float2bfloat16(v);
  return *reinterpret_cast<ushort*>(&b);
}
__device__ __forceinline__ float us2f(ushort u) {
  __hip_bfloat16 b;
  *reinterpret_cast<ushort*>(&b) = u;
  return __bfloat162float(b);
}
__device__ __forceinline__ void cvt_hilo(float v, ushort& h, ushort& l) {
  __hip_bfloat16 bh = __float2bfloat16(v);
  float r = v - __bfloat162float(bh);
  __hip_bfloat16 bl = __float2bfloat16(r);
  h = *reinterpret_cast<ushort*>(&bh);
  l = *reinterpret_cast<ushort*>(&bl);
}
__device__ __forceinline__ void stage4(ushort* hi, ushort* lo, const float* src) {
  float4 v = *(const float4*)src;
  float a[4] = {v.x, v.y, v.z, v.w};
#pragma unroll
  for (int j = 0; j < 4; ++j) { ushort h, l; cvt_hilo(a[j], h, l); hi[j] = h; lo[j] = l; }
}
// write-through store to LLC (no dirty L2 line)
__device__ __forceinline__ void st_wt(ushort* p, ushort v) {
  __hip_atomic_store(p, v, __ATOMIC_RELAXED, __HIP_MEMORY_SCOPE_AGENT);
}
// LLC-coherent 16B read as two 8B relaxed agent atomic loads (pipelined)
__device__ __forceinline__ v8s ld_a16(const ushort* p) {
  u64 a = __hip_atomic_load((const u64*)p, __ATOMIC_RELAXED, __HIP_MEMORY_SCOPE_AGENT);
  u64 b = __hip_atomic_load((const u64*)p + 1, __ATOMIC_RELAXED, __HIP_MEMORY_SCOPE_AGENT);
  union { u64 u[2]; v8s v; } r;
  r.u[0] = a; r.u[1] = b;
  return r.v;
}

__device__ __forceinline__ int poll_ge(const int* p, int tgt, long& budget) {
  while (budget > 0) {
    if (__hip_atomic_load(p, __ATOMIC_RELAXED, __HIP_MEMORY_SCOPE_AGENT) >= tgt) return 1;
    __builtin_amdgcn_s_sleep(1);
    --budget;
  }
  return 0;
}

__global__ void __launch_bounds__(256, 1) rnn_persistent(
    const int* __restrict__ tok,        // [128][2048] int32
    const float* __restrict__ emb,      // [32000][256] f32
    const float* __restrict__ gwih,     // [1536][256]
    const float* __restrict__ gwhh,     // [1536][512]
    const float* __restrict__ gb,       // [1536]
    const float* __restrict__ gbn,      // [512]
    const float* __restrict__ lwih,     // [2048][512]
    const float* __restrict__ lwhh,     // [2048][512]
    const float* __restrict__ lb,       // [2048]
    char* __restrict__ ws,
    int hstride, int has_lo)            // 1024/1 (full) or 512/0 (small ws)
{
  extern __shared__ char smem[];
  const int tid  = threadIdx.x;
  const int wgid = blockIdx.x;
  const bool is_gru = (wgid < 128);
  const int sub = wgid & 127;
  const int bg  = sub & 1;           // batch rows [bg*64, bg*64+64)
  const int cg  = sub >> 1;          // cols [cg*8, cg*8+8)
  const int colbase = cg * 8;
  const int b0 = bg * 64;
  const int lane = tid & 63;
  const int wave = tid >> 6;         // M-tile index 0..3
  const int quad = lane >> 4;
  const int r16  = lane & 15;
  const int c8   = lane & 7;
  const bool hi_lane = ((lane & 8) == 0);

  int* cnt = (int*)ws;
  int* gru_done  = cnt + bg * 64;          // 256B apart per bg
  int* lstm_done = cnt + 512 + bg * 64;
  int* boot      = cnt + 1024;
  ushort* ring = (ushort*)(ws + RING_OFF);
  const int slotE = 128 * hstride;         // elems per h time-slot
  ushort* hlb = ring + 2 * slotE;          // LSTM h, 2 parities

  const int mrow  = wave * 16 + r16;            // A row in 64-row group
  const int bglob = b0 + wave * 16 + quad * 4;  // +rg = global batch row
  long budget = 20000000;

  if (is_gru) {
    // LDS (ushort idx): wih hi[24][264]@0, lo@6336; whh hi[24][520]@12672, lo@25152
    ushort* smemU = (ushort*)smem;
    const int WIH_HI = 0, WIH_LO = 6336, WHH_HI = 12672, WHH_LO = 25152;
    int* tokbuf = (int*)(smem + 75264);
    int* okf    = (int*)(smem + 75264 + 256);

    for (int i = tid; i < 24 * 64; i += 256) {       // wih: 256 K, 4 f32/chunk
      int row = i >> 6, q = (i & 63) * 4;
      int gate = row >> 3, col = colbase + (row & 7);
      stage4(&smemU[WIH_HI + row * 264 + q], &smemU[WIH_LO + row * 264 + q],
             gwih + (long)(gate * 512 + col) * 256 + q);
    }
    for (int i = tid; i < 24 * 128; i += 256) {      // whh: 512 K
      int row = i >> 7, k = (i & 127) * 4;
      int gate = row >> 3, col = colbase + (row & 7);
      stage4(&smemU[WHH_HI + row * 520 + k], &smemU[WHH_LO + row * 520 + k],
             gwhh + (long)(gate * 512 + col) * 512 + k);
    }
    const float b_r  = gb[colbase + c8];
    const float b_z  = gb[512 + colbase + c8];
    const float b_in = gb[1024 + colbase + c8];
    const float bnv  = gbn[colbase + c8];
    if (tid < 64) tokbuf[tid] = tok[(b0 + tid) * T_STEPS + 0];
    __syncthreads();

    // boot: RELEASE add (one-time wbl2 -> flushes any stale dirty ws lines)
    if (tid == 0) {
      __hip_atomic_fetch_add(boot, 1, __ATOMIC_RELEASE, __HIP_MEMORY_SCOPE_AGENT);
      long bb = 3000000;
      okf[0] = poll_ge(boot, 256, bb);
    }
    __syncthreads();
    if (!okf[0]) { if (wgid == 0 && tid == 0) st_wt(&hlb[slotE + 0], f2us(1.0e4f)); return; }

    v4f acc_rz, acc_nx;                         // x-side accs, carried to next t
    float hgreg[4] = {0.f, 0.f, 0.f, 0.f};

    auto acc_x = [&]() {                        // x-GEMM: on-the-fly hi/lo of emb
      acc_rz = v4zero(); acc_nx = v4zero();
      const float* xrow = emb + (long)tokbuf[mrow] * 256;
#pragma unroll
      for (int kk = 0; kk < 8; ++kk) {
        float4 xa = *(const float4*)(xrow + kk * 32 + quad * 8);
        float4 xb = *(const float4*)(xrow + kk * 32 + quad * 8 + 4);
        float xv[8] = {xa.x, xa.y, xa.z, xa.w, xb.x, xb.y, xb.z, xb.w};
        v8s ahi, alo;
#pragma unroll
        for (int j = 0; j < 8; ++j) { ushort h, l; cvt_hilo(xv[j], h, l); ahi[j] = (short)h; alo[j] = (short)l; }
        const int o0 = r16 * 264 + kk * 32 + quad * 8;
        const int o1 = (16 + c8) * 264 + kk * 32 + quad * 8;
        v8s b0h = *(const v8s*)&smemU[WIH_HI + o0], b0l = *(const v8s*)&smemU[WIH_LO + o0];
        v8s b1h = *(const v8s*)&smemU[WIH_HI + o1], b1l = *(const v8s*)&smemU[WIH_LO + o1];
        acc_rz = MFMA16(ahi, b0h, acc_rz); acc_rz = MFMA16(alo, b0h, acc_rz); acc_rz = MFMA16(ahi, b0l, acc_rz);
        acc_nx = MFMA16(ahi, b1h, acc_nx); acc_nx = MFMA16(alo, b1h, acc_nx); acc_nx = MFMA16(ahi, b1l, acc_nx);
      }
    };
    acc_x();  // t=0

    for (int t = 0; t < T_STEPS; ++t) {
      // poll peers (own-bg GRU step t-1 done; LSTM step t-2 done). No fence:
      // all exchange reads below are LLC-coherent atomic loads.
      if (tid == 0) {
        int ok = poll_ge(gru_done, 64 * t, budget);
        if (ok) ok = poll_ge(lstm_done, 64 * (t - 1), budget);
        okf[0] = ok;
      }
      __syncthreads();
      if (!okf[0]) { if (tid == 0) st_wt(&hlb[slotE + 2 + wgid], f2us(100.f)); break; }

      int tkn = 0;
      if (tid < 64 && t + 1 < T_STEPS) tkn = tok[(b0 + tid) * T_STEPS + t + 1];

      v4f acc_nh = v4zero();
      if (t > 0) {
        const ushort* hrow = ring + ((t - 1) & 1) * slotE + (b0 + mrow) * hstride;
#pragma unroll 4
        for (int kk = 0; kk < 16; ++kk) {
          v8s ahi = ld_a16(&hrow[kk * 32 + quad * 8]);
          const int o0 = r16 * 520 + kk * 32 + quad * 8;
          const int o1 = (16 + c8) * 520 + kk * 32 + quad * 8;
          v8s b0h = *(const v8s*)&smemU[WHH_HI + o0], b0l = *(const v8s*)&smemU[WHH_LO + o0];
          v8s b1h = *(const v8s*)&smemU[WHH_HI + o1], b1l = *(const v8s*)&smemU[WHH_LO + o1];
          acc_rz = MFMA16(ahi, b0h, acc_rz); acc_rz = MFMA16(ahi, b0l, acc_rz);
          acc_nh = MFMA16(ahi, b1h, acc_nh); acc_nh = MFMA16(ahi, b1l, acc_nh);
          if (has_lo) {
            v8s alo = ld_a16(&hrow[512 + kk * 32 + quad * 8]);
            acc_rz = MFMA16(alo, b0h, acc_rz);
            acc_nh = MFMA16(alo, b1h, acc_nh);
          }
        }
      }

      ushort* slotT = ring + (t & 1) * slotE;
#pragma unroll
      for (int rg = 0; rg < 4; ++rg) {
        float vrz = acc_rz[rg];
        float oth = __shfl_xor(vrz, 8);
        float rv = (lane & 8) ? oth : vrz;
        float zv = (lane & 8) ? vrz : oth;
        float r = sigf(rv + b_r), z = sigf(zv + b_z);
        float nn = tanhf_fast(acc_nx[rg] + b_in + r * (acc_nh[rg] + bnv));
        float hnew = nn + z * (hgreg[rg] - nn);
        hgreg[rg] = hnew;
        ushort uh = f2us(hnew);
        const int rb = (bglob + rg) * hstride;
        if (hi_lane) st_wt(&slotT[rb + colbase + c8], uh);
        else if (has_lo) st_wt(&slotT[rb + 512 + colbase + c8], f2us(hnew - us2f(uh)));
      }
      if (tid < 64 && t + 1 < T_STEPS) tokbuf[tid] = tkn;

      // release: barrier drains write-through stores to LLC; RELAXED add (no wbl2)
      __syncthreads();
      if (tid == 0)
        __hip_atomic_fetch_add(gru_done, 1, __ATOMIC_RELAXED, __HIP_MEMORY_SCOPE_AGENT);
      if (t + 1 < T_STEPS) acc_x();
    }
  } else {
    // ---------------- LSTM ----------------
    // LDS: wl hi[32][1032]@0 ([0,512)=wih K, [512,1024)=whh K), lo@33024
    ushort* smemU = (ushort*)smem;
    const int WL_HI = 0, WL_LO = 33024;
    int* okf = (int*)(smem + 132096);

    for (int i = tid; i < 32 * 256; i += 256) {
      int row = i >> 8, k = (i & 255) * 4;
      int gate = row >> 3, col = colbase + (row & 7);
      long grow = gate * 512 + col;
      const float* src = (k < 512) ? (lwih + grow * 512 + k) : (lwhh + grow * 512 + (k - 512));
      stage4(&smemU[WL_HI + row * 1032 + k], &smemU[WL_LO + row * 1032 + k], src);
    }
    const float b_i = lb[colbase + c8];
    const float b_f = lb[512 + colbase + c8];
    const float b_g = lb[1024 + colbase + c8];
    const float b_o = lb[1536 + colbase + c8];
    __syncthreads();

    if (tid == 0) {
      __hip_atomic_fetch_add(boot, 1, __ATOMIC_RELEASE, __HIP_MEMORY_SCOPE_AGENT);
      long bb = 3000000;
      okf[0] = poll_ge(boot, 256, bb);
    }
    __syncthreads();
    if (!okf[0]) { if (wgid == 128 && tid == 0) st_wt(&hlb[slotE + 1], f2us(1.0e4f)); return; }

    float creg[4] = {0.f, 0.f, 0.f, 0.f};

    for (int t = 0; t < T_STEPS; ++t) {
      if (tid == 0) {
        int ok = poll_ge(gru_done, 64 * (t + 1), budget);
        if (ok) ok = poll_ge(lstm_done, 64 * t, budget);
        okf[0] = ok;
      }
      __syncthreads();
      if (!okf[0]) { if (tid == 0) st_wt(&hlb[slotE + 2 + wgid], f2us(100.f)); break; }

      v4f a0 = v4zero(), a1 = v4zero();
      { // hg(t): ring slot t&1, weight K offset 0
        const ushort* hrow = ring + (t & 1) * slotE + (b0 + mrow) * hstride;
#pragma unroll 4
        for (int kk = 0; kk < 16; ++kk) {
          v8s ahi = ld_a16(&hrow[kk * 32 + quad * 8]);
          const int o0 = r16 * 1032 + kk * 32 + quad * 8;
          const int o1 = (16 + r16) * 1032 + kk * 32 + quad * 8;
          v8s b0h = *(const v8s*)&smemU[WL_HI + o0], b0l = *(const v8s*)&smemU[WL_LO + o0];
          v8s b1h = *(const v8s*)&smemU[WL_HI + o1], b1l = *(const v8s*)&smemU[WL_LO + o1];
          a0 = MFMA16(ahi, b0h, a0); a0 = MFMA16(ahi, b0l, a0);
          a1 = MFMA16(ahi, b1h, a1); a1 = MFMA16(ahi, b1l, a1);
          if (has_lo) {
            v8s alo = ld_a16(&hrow[512 + kk * 32 + quad * 8]);
            a0 = MFMA16(alo, b0h, a0);
            a1 = MFMA16(alo, b1h, a1);
          }
        }
      }
      if (t > 0) { // hl(t-1): parity (t-1)&1, weight K offset 512
        const ushort* hrow = hlb + ((t - 1) & 1) * slotE + (b0 + mrow) * hstride;
#pragma unroll 4
        for (int kk = 0; kk < 16; ++kk) {
          v8s ahi = ld_a16(&hrow[kk * 32 + quad * 8]);
          const int o0 = r16 * 1032 + 512 + kk * 32 + quad * 8;
          const int o1 = (16 + r16) * 1032 + 512 + kk * 32 + quad * 8;
          v8s b0h = *(const v8s*)&smemU[WL_HI + o0], b0l = *(const v8s*)&smemU[WL_LO + o0];
          v8s b1h = *(const v8s*)&smemU[WL_HI + o1], b1l = *(const v8s*)&smemU[WL_LO + o1];
          a0 = MFMA16(ahi, b0h, a0); a0 = MFMA16(ahi, b0l, a0);
          a1 = MFMA16(ahi, b1h, a1); a1 = MFMA16(ahi, b1l, a1);
          if (has_lo) {
            v8s alo = ld_a16(&hrow[512 + kk * 32 + quad * 8]);
            a0 = MFMA16(alo, b0h, a0);
            a1 = MFMA16(alo, b1h, a1);
          }
        }
      }

      ushort* hout = hlb + (t & 1) * slotE;
#pragma unroll
      for (int rg = 0; rg < 4; ++rg) {
        float vif = a0[rg];
        float o1v = __shfl_xor(vif, 8);
        float iv = (lane & 8) ? o1v : vif;
        float fv = (lane & 8) ? vif : o1v;
        float vgo = a1[rg];
        float o2v = __shfl_xor(vgo, 8);
        float gv = (lane & 8) ? o2v : vgo;
        float ov = (lane & 8) ? vgo : o2v;
        float i_ = sigf(iv + b_i), f_ = sigf(fv + b_f);
        float g_ = tanhf_fast(gv + b_g), o_ = sigf(ov + b_o);
        float cn = f_ * creg[rg] + i_ * g_;
        creg[rg] = cn;
        float hv = o_ * tanhf_fast(cn);
        ushort uh = f2us(hv);
        const int rb = (bglob + rg) * hstride;
        if (hi_lane) st_wt(&hout[rb + colbase + c8], uh);
        else if (has_lo) st_wt(&hout[rb + 512 + colbase + c8], f2us(hv - us2f(uh)));
      }

      __syncthreads();
      if (tid == 0)
        __hip_atomic_fetch_add(lstm_done, 1, __ATOMIC_RELAXED, __HIP_MEMORY_SCOPE_AGENT);
    }
  }
}

// out = h_final @ head_w.T + head_b (f32). h_final = hl parity 1 hi(+lo),
// read via LLC-coherent atomic loads (no reliance on L2 state).
__global__ void head_kernel(const char* __restrict__ ws,
                            const float* __restrict__ hw,   // [6][512]
                            const float* __restrict__ hbias,// [6]
                            float* __restrict__ out,        // [128][6]
                            int hstride, int has_lo) {
  const ushort* h1 = (const ushort*)(ws + RING_OFF) + 3 * 128 * hstride;
  const int b = blockIdx.x, l = threadIdx.x;   // 64 threads; lane l owns k=l*8..l*8+7
  const int k0 = l * 8;
  v8s hi = ld_a16(&h1[b * hstride + k0]);
  v8s lo;
  if (has_lo) lo = ld_a16(&h1[b * hstride + 512 + k0]);
  float acc[6] = {0.f, 0.f, 0.f, 0.f, 0.f, 0.f};
#pragma unroll
  for (int j = 0; j < 8; ++j) {
    float h = us2f((ushort)hi[j]);
    if (has_lo) h += us2f((ushort)lo[j]);
#pragma unroll
    for (int o = 0; o < 6; ++o) acc[o] += h * hw[o * 512 + k0 + j];
  }
#pragma unroll
  for (int o = 0; o < 6; ++o) {
    float v = acc[o];
    for (int off = 32; off > 0; off >>= 1) v += __shfl_down(v, off);
    if (l == 0) out[b * 6 + o] = v + hbias[o];
  }
}

// zero the counter region with write-through stores (no cached ws lines)
__global__ void init_ws(int* cnt) {
  int i = blockIdx.x * blockDim.x + threadIdx.x;
  if (i < 2048)
    __hip_atomic_store(cnt + i, 0, __ATOMIC_RELAXED, __HIP_MEMORY_SCOPE_AGENT);
}

__global__ void ws_too_small_marker(float* out) {
  if (threadIdx.x == 0 && blockIdx.x == 0) out[0] = 12345.0f;
}

extern "C" void kernel_launch(void* const* d_in, const int* in_sizes, int n_in,
                              void* d_out, int out_size, void* d_ws, size_t ws_size,
                              hipStream_t stream) {
  const int*   tok  = (const int*)d_in[0];
  const float* emb  = (const float*)d_in[1];
  const float* gwih = (const float*)d_in[2];
  const float* gwhh = (const float*)d_in[3];
  const float* gb   = (const float*)d_in[4];
  const float* gbn  = (const float*)d_in[5];
  const float* lwih = (const float*)d_in[6];
  const float* lwhh = (const float*)d_in[7];
  const float* lb   = (const float*)d_in[8];
  const float* hw   = (const float*)d_in[9];
  const float* hb   = (const float*)d_in[10];

  (void)in_sizes; (void)n_in; (void)out_size;

  const size_t WS_A = (size_t)RING_OFF + 4ull * 128 * 1024 * 2;  // 1,056,768
  const size_t WS_B = (size_t)RING_OFF + 4ull * 128 * 512 * 2;   //   532,480
  if (ws_size < WS_B) {
    hipLaunchKernelGGL(ws_too_small_marker, dim3(1), dim3(64), 0, stream, (float*)d_out);
    return;
  }
  const int has_lo  = (ws_size >= (size_t)WS_A) ? 1 : 0;
  const int hstride = has_lo ? 1024 : 512;

  (void)hipFuncSetAttribute(reinterpret_cast<const void*>(rnn_persistent),
                            hipFuncAttributeMaxDynamicSharedMemorySize, DYN_LDS);
  hipLaunchKernelGGL(init_ws, dim3(8), dim3(256), 0, stream, (int*)d_ws);
  hipLaunchKernelGGL(rnn_persistent, dim3(256), dim3(256), DYN_LDS, stream,
                     tok, emb, gwih, gwhh, gb, gbn, lwih, lwhh, lb,
                     (char*)d_ws, hstride, has_lo);
  hipLaunchKernelGGL(head_kernel, dim3(128), dim3(64), 0, stream,
                     (const char*)d_ws, hw, hb, (float*)d_out, hstride, has_lo);
}

// Round 9
// 44739.816 us; speedup vs baseline: 1.0441x; 1.0441x over previous
//
#include <hip/hip_runtime.h>
#include <hip/hip_bf16.h>

// ---------------------------------------------------------------------------
// RecurrentCellsModel: emb lookup -> GRU scan -> LSTM scan -> linear head.
// B=128, T=2048, D=256, H=512, O=6. Float tensors f32, tokens int32.
// No fp32 MFMA on CDNA4 -> hi+lo bf16 split (~2^-17 rel err).
//
// R8 post-mortem: removing all cache maintenance was NEUTRAL (45->46.7ms).
// Revised model: agent atomic loads = global_load sc0 sc1 (coalesced, LLC-
// direct); bottleneck = 48MB/step exchange reads over XCD<->LLC fabric
// (~16us) + handoff (~6us). R9 halves volume via fatter col-slices
// (per-WG read volume = rows x K, independent of cols):
//   - GRU: 16 cols/WG, 64 WGs, hi+lo weights (147KB LDS).  16->8 MB/step.
//   - LSTM: 16 cols/WG, 64 WGs, HI-ONLY weights (129KB).   32->16 MB/step.
//     (weight-lo drop = fixed 2^-9 W perturbation, est +1e-4 absmax;
//      h exchange stays hi+lo = fp32-accurate.)
//   - 16-wide N-tile = one gate -> epilogue shuffles deleted.
//   - striped done-counters (4 lines, 8 adders each) + s_sleep(4) polls.
// Grid: 128 WGs x 256 thr, DYN_LDS 150816 => 1 WG/CU.
//
// MFMA 16x16x32 bf16 layouts (HW-verified m89/m91/m120):
//   A: a[j]=A[m=lane&15][k=(lane>>4)*8+j]; B: b[j]=B[k=(lane>>4)*8+j][n=lane&15];
//   D: d[reg]=D[row=(lane>>4)*4+reg][col=lane&15].
//
// Fingerprints: 12345 = ws too small; ~1e4 = boot timeout; ~1e2 = stall;
// 0.0476 = h_final zeros (e.g. rnn launch failure).
// ---------------------------------------------------------------------------

typedef short v8s __attribute__((ext_vector_type(8)));
typedef float v4f __attribute__((ext_vector_type(4)));
typedef unsigned long long u64;

#define T_STEPS 2048
#define RING_OFF 8192
#define DYN_LDS 150816

#define MFMA16(a, b, c) __builtin_amdgcn_mfma_f32_16x16x32_bf16((a), (b), (c), 0, 0, 0)

__device__ __forceinline__ v4f v4zero() { v4f z = {0.f, 0.f, 0.f, 0.f}; return z; }
__device__ __forceinline__ float sigf(float x) { return 1.f / (1.f + __expf(-x)); }
__device__ __forceinline__ float tanhf_fast(float x) { return 1.f - 2.f / (1.f + __expf(2.f * x)); }

__device__ __forceinline__ ushort f2us(float v) {
  __hip_bfloat16 b = __float2bfloat16(v);
  return *reinterpret_cast<ushort*>(&b);
}
__device__ __forceinline__ float us2f(ushort u) {
  __hip_bfloat16 b;
  *reinterpret_cast<ushort*>(&b) = u;
  return __bfloat162float(b);
}
__device__ __forceinline__ void cvt_hilo(float v, ushort& h, ushort& l) {
  __hip_bfloat16 bh = __float2bfloat16(v);
  float r = v - __bfloat162float(bh);
  __hip_bfloat16 bl = __float2bfloat16(r);
  h = *reinterpret_cast<ushort*>(&bh);
  l = *reinterpret_cast<ushort*>(&bl);
}
__device__ __forceinline__ void stage4(ushort* hi, ushort* lo, const float* src) {
  float4 v = *(const float4*)src;
  float a[4] = {v.x, v.y, v.z, v.w};
#pragma unroll
  for (int j = 0; j < 4; ++j) { ushort h, l; cvt_hilo(a[j], h, l); hi[j] = h; lo[j] = l; }
}
__device__ __forceinline__ void stage4h(ushort* hi, const float* src) {  // hi only
  float4 v = *(const float4*)src;
  float a[4] = {v.x, v.y, v.z, v.w};
#pragma unroll
  for (int j = 0; j < 4; ++j) hi[j] = f2us(a[j]);
}
// write-through store to LLC (no dirty L2 line)
__device__ __forceinline__ void st_wt(ushort* p, ushort v) {
  __hip_atomic_store(p, v, __ATOMIC_RELAXED, __HIP_MEMORY_SCOPE_AGENT);
}
// LLC-coherent 16B read (2 x 8B sc0/sc1 loads, coalesced+pipelined)
__device__ __forceinline__ v8s ld_a16(const ushort* p) {
  u64 a = __hip_atomic_load((const u64*)p, __ATOMIC_RELAXED, __HIP_MEMORY_SCOPE_AGENT);
  u64 b = __hip_atomic_load((const u64*)p + 1, __ATOMIC_RELAXED, __HIP_MEMORY_SCOPE_AGENT);
  union { u64 u[2]; v8s v; } r;
  r.u[0] = a; r.u[1] = b;
  return r.v;
}

__device__ __forceinline__ int poll_ge(const int* p, int tgt, long& budget) {
  while (budget > 0) {
    if (__hip_atomic_load(p, __ATOMIC_RELAXED, __HIP_MEMORY_SCOPE_AGENT) >= tgt) return 1;
    __builtin_amdgcn_s_sleep(1);
    --budget;
  }
  return 0;
}
// striped counter: 4 words, 256B apart; sum must reach tgt
__device__ __forceinline__ int poll4_ge(const int* base, int tgt, long& budget) {
  while (budget > 0) {
    int s = __hip_atomic_load(base,       __ATOMIC_RELAXED, __HIP_MEMORY_SCOPE_AGENT)
          + __hip_atomic_load(base +  64, __ATOMIC_RELAXED, __HIP_MEMORY_SCOPE_AGENT)
          + __hip_atomic_load(base + 128, __ATOMIC_RELAXED, __HIP_MEMORY_SCOPE_AGENT)
          + __hip_atomic_load(base + 192, __ATOMIC_RELAXED, __HIP_MEMORY_SCOPE_AGENT);
    if (s >= tgt) return 1;
    __builtin_amdgcn_s_sleep(4);
    --budget;
  }
  return 0;
}

__global__ void __launch_bounds__(256, 1) rnn_persistent(
    const int* __restrict__ tok,        // [128][2048] int32
    const float* __restrict__ emb,      // [32000][256] f32
    const float* __restrict__ gwih,     // [1536][256]
    const float* __restrict__ gwhh,     // [1536][512]
    const float* __restrict__ gb,       // [1536]
    const float* __restrict__ gbn,      // [512]
    const float* __restrict__ lwih,     // [2048][512]
    const float* __restrict__ lwhh,     // [2048][512]
    const float* __restrict__ lb,       // [2048]
    char* __restrict__ ws,
    int hstride, int has_lo)            // 1024/1 (full) or 512/0 (small ws)
{
  extern __shared__ char smem[];
  const int tid  = threadIdx.x;
  const int wgid = blockIdx.x;
  const bool is_gru = (wgid < 64);
  const int sub = is_gru ? wgid : (wgid - 64);
  const int bg  = sub & 1;           // batch rows [bg*64, bg*64+64)
  const int cg  = sub >> 1;          // col group 0..31, 16 cols each
  const int colbase = cg * 16;
  const int b0 = bg * 64;
  const int stripe = cg & 3;
  const int lane = tid & 63;
  const int wave = tid >> 6;         // M-tile index 0..3
  const int quad = lane >> 4;
  const int r16  = lane & 15;

  int* cnt = (int*)ws;
  int* gru_done  = cnt + bg * 256;           // 4 stripes @ +0,+64,+128,+192
  int* lstm_done = cnt + 512 + bg * 256;
  int* boot      = cnt + 1024;
  ushort* ring = (ushort*)(ws + RING_OFF);
  const int slotE = 128 * hstride;           // elems per h time-slot
  ushort* hlb = ring + 2 * slotE;            // LSTM h, 2 parities

  const int mrow  = wave * 16 + r16;            // A row in 64-row group
  const int bglob = b0 + wave * 16 + quad * 4;  // +rg = global batch row
  const int col   = colbase + r16;              // this lane's output column
  long budget = 3000000;

  if (is_gru) {
    // LDS (ushort idx): wih hi[48][264]@0, lo@12672; whh hi[48][520]@25344, lo@50304
    ushort* smemU = (ushort*)smem;
    const int WIH_HI = 0, WIH_LO = 12672, WHH_HI = 25344, WHH_LO = 50304;
    int* tokbuf = (int*)(smem + 150528);
    int* okf    = (int*)(smem + 150528 + 256);

    for (int i = tid; i < 48 * 64; i += 256) {       // wih: 256 K, 4 f32/chunk
      int row = i >> 6, q = (i & 63) * 4;
      int gate = row >> 4, c = colbase + (row & 15);
      stage4(&smemU[WIH_HI + row * 264 + q], &smemU[WIH_LO + row * 264 + q],
             gwih + (long)(gate * 512 + c) * 256 + q);
    }
    for (int i = tid; i < 48 * 128; i += 256) {      // whh: 512 K
      int row = i >> 7, k = (i & 127) * 4;
      int gate = row >> 4, c = colbase + (row & 15);
      stage4(&smemU[WHH_HI + row * 520 + k], &smemU[WHH_LO + row * 520 + k],
             gwhh + (long)(gate * 512 + c) * 512 + k);
    }
    const float b_r  = gb[col];
    const float b_z  = gb[512 + col];
    const float b_in = gb[1024 + col];
    const float bnv  = gbn[col];
    if (tid < 64) tokbuf[tid] = tok[(b0 + tid) * T_STEPS + 0];
    __syncthreads();

    if (tid == 0) {
      __hip_atomic_fetch_add(boot, 1, __ATOMIC_RELEASE, __HIP_MEMORY_SCOPE_AGENT);
      long bb = 3000000;
      okf[0] = poll_ge(boot, 128, bb);
    }
    __syncthreads();
    if (!okf[0]) { if (wgid == 0 && tid == 0) st_wt(&hlb[slotE + 0], f2us(1.0e4f)); return; }

    v4f acc_r, acc_z, acc_nx;                   // r,z carry x+h; nx = x-part of n
    float hgreg[4] = {0.f, 0.f, 0.f, 0.f};

    auto acc_x = [&]() {                        // x-GEMM: on-the-fly hi/lo of emb
      acc_r = v4zero(); acc_z = v4zero(); acc_nx = v4zero();
      const float* xrow = emb + (long)tokbuf[mrow] * 256;
#pragma unroll
      for (int kk = 0; kk < 8; ++kk) {
        float4 xa = *(const float4*)(xrow + kk * 32 + quad * 8);
        float4 xb = *(const float4*)(xrow + kk * 32 + quad * 8 + 4);
        float xv[8] = {xa.x, xa.y, xa.z, xa.w, xb.x, xb.y, xb.z, xb.w};
        v8s ahi, alo;
#pragma unroll
        for (int j = 0; j < 8; ++j) { ushort h, l; cvt_hilo(xv[j], h, l); ahi[j] = (short)h; alo[j] = (short)l; }
        const int orr = (r16) * 264 + kk * 32 + quad * 8;
        const int oz  = (16 + r16) * 264 + kk * 32 + quad * 8;
        const int on  = (32 + r16) * 264 + kk * 32 + quad * 8;
        v8s brh = *(const v8s*)&smemU[WIH_HI + orr], brl = *(const v8s*)&smemU[WIH_LO + orr];
        v8s bzh = *(const v8s*)&smemU[WIH_HI + oz],  bzl = *(const v8s*)&smemU[WIH_LO + oz];
        v8s bnh = *(const v8s*)&smemU[WIH_HI + on],  bnl = *(const v8s*)&smemU[WIH_LO + on];
        acc_r = MFMA16(ahi, brh, acc_r); acc_r = MFMA16(alo, brh, acc_r); acc_r = MFMA16(ahi, brl, acc_r);
        acc_z = MFMA16(ahi, bzh, acc_z); acc_z = MFMA16(alo, bzh, acc_z); acc_z = MFMA16(ahi, bzl, acc_z);
        acc_nx = MFMA16(ahi, bnh, acc_nx); acc_nx = MFMA16(alo, bnh, acc_nx); acc_nx = MFMA16(ahi, bnl, acc_nx);
      }
    };
    acc_x();  // t=0

    for (int t = 0; t < T_STEPS; ++t) {
      // need: own-bg GRU step t-1 done (32 cgs); LSTM step t-2 done (ring bp)
      if (tid == 0) {
        int ok = poll4_ge(gru_done, 32 * t, budget);
        if (ok) ok = poll4_ge(lstm_done, 32 * (t - 1), budget);
        okf[0] = ok;
      }
      __syncthreads();
      if (!okf[0]) { if (tid == 0) st_wt(&hlb[slotE + 2 + wgid], f2us(100.f)); break; }

      int tkn = 0;
      if (tid < 64 && t + 1 < T_STEPS) tkn = tok[(b0 + tid) * T_STEPS + t + 1];

      v4f acc_nh = v4zero();
      if (t > 0) {
        const ushort* hrow = ring + ((t - 1) & 1) * slotE + (b0 + mrow) * hstride;
#pragma unroll 4
        for (int kk = 0; kk < 16; ++kk) {
          v8s ahi = ld_a16(&hrow[kk * 32 + quad * 8]);
          const int orr = (r16) * 520 + kk * 32 + quad * 8;
          const int oz  = (16 + r16) * 520 + kk * 32 + quad * 8;
          const int on  = (32 + r16) * 520 + kk * 32 + quad * 8;
          v8s brh = *(const v8s*)&smemU[WHH_HI + orr], brl = *(const v8s*)&smemU[WHH_LO + orr];
          v8s bzh = *(const v8s*)&smemU[WHH_HI + oz],  bzl = *(const v8s*)&smemU[WHH_LO + oz];
          v8s bnh = *(const v8s*)&smemU[WHH_HI + on],  bnl = *(const v8s*)&smemU[WHH_LO + on];
          acc_r = MFMA16(ahi, brh, acc_r); acc_r = MFMA16(ahi, brl, acc_r);
          acc_z = MFMA16(ahi, bzh, acc_z); acc_z = MFMA16(ahi, bzl, acc_z);
          acc_nh = MFMA16(ahi, bnh, acc_nh); acc_nh = MFMA16(ahi, bnl, acc_nh);
          if (has_lo) {
            v8s alo = ld_a16(&hrow[512 + kk * 32 + quad * 8]);
            acc_r = MFMA16(alo, brh, acc_r);
            acc_z = MFMA16(alo, bzh, acc_z);
            acc_nh = MFMA16(alo, bnh, acc_nh);
          }
        }
      }

      ushort* slotT = ring + (t & 1) * slotE;
#pragma unroll
      for (int rg = 0; rg < 4; ++rg) {
        float r = sigf(acc_r[rg] + b_r);
        float z = sigf(acc_z[rg] + b_z);
        float nn = tanhf_fast(acc_nx[rg] + b_in + r * (acc_nh[rg] + bnv));
        float hnew = nn + z * (hgreg[rg] - nn);
        hgreg[rg] = hnew;
        ushort uh = f2us(hnew);
        const int rb = (bglob + rg) * hstride;
        st_wt(&slotT[rb + col], uh);
        if (has_lo) st_wt(&slotT[rb + 512 + col], f2us(hnew - us2f(uh)));
      }
      if (tid < 64 && t + 1 < T_STEPS) tokbuf[tid] = tkn;

      __syncthreads();   // drains all waves' write-through stores
      if (tid == 0)
        __hip_atomic_fetch_add(gru_done + stripe * 64, 1, __ATOMIC_RELAXED, __HIP_MEMORY_SCOPE_AGENT);
      if (t + 1 < T_STEPS) acc_x();   // next step's x-part in the flag shadow
    }
  } else {
    // ---------------- LSTM: 16 cols, HI-ONLY weights ----------------
    // LDS: wl hi[64][1032] ([0,512)=wih K over hg, [512,1024)=whh K over hl)
    ushort* smemU = (ushort*)smem;
    int* okf = (int*)(smem + 132096);

    for (int i = tid; i < 64 * 256; i += 256) {
      int row = i >> 8, k = (i & 255) * 4;
      int gate = row >> 4, c = colbase + (row & 15);
      long grow = gate * 512 + c;
      const float* src = (k < 512) ? (lwih + grow * 512 + k) : (lwhh + grow * 512 + (k - 512));
      stage4h(&smemU[row * 1032 + k], src);
    }
    const float b_i = lb[col];
    const float b_f = lb[512 + col];
    const float b_g = lb[1024 + col];
    const float b_o = lb[1536 + col];
    __syncthreads();

    if (tid == 0) {
      __hip_atomic_fetch_add(boot, 1, __ATOMIC_RELEASE, __HIP_MEMORY_SCOPE_AGENT);
      long bb = 3000000;
      okf[0] = poll_ge(boot, 128, bb);
    }
    __syncthreads();
    if (!okf[0]) { if (wgid == 64 && tid == 0) st_wt(&hlb[slotE + 1], f2us(1.0e4f)); return; }

    float creg[4] = {0.f, 0.f, 0.f, 0.f};

    for (int t = 0; t < T_STEPS; ++t) {
      if (tid == 0) {
        int ok = poll4_ge(gru_done, 32 * (t + 1), budget);
        if (ok) ok = poll4_ge(lstm_done, 32 * t, budget);
        okf[0] = ok;
      }
      __syncthreads();
      if (!okf[0]) { if (tid == 0) st_wt(&hlb[slotE + 2 + wgid], f2us(100.f)); break; }

      v4f ai = v4zero(), af = v4zero(), ag = v4zero(), ao = v4zero();
      { // hg(t): ring slot t&1, weight K offset 0
        const ushort* hrow = ring + (t & 1) * slotE + (b0 + mrow) * hstride;
#pragma unroll 4
        for (int kk = 0; kk < 16; ++kk) {
          v8s ahi = ld_a16(&hrow[kk * 32 + quad * 8]);
          v8s bi = *(const v8s*)&smemU[(r16) * 1032 + kk * 32 + quad * 8];
          v8s bf = *(const v8s*)&smemU[(16 + r16) * 1032 + kk * 32 + quad * 8];
          v8s bgv = *(const v8s*)&smemU[(32 + r16) * 1032 + kk * 32 + quad * 8];
          v8s bo = *(const v8s*)&smemU[(48 + r16) * 1032 + kk * 32 + quad * 8];
          ai = MFMA16(ahi, bi, ai); af = MFMA16(ahi, bf, af);
          ag = MFMA16(ahi, bgv, ag); ao = MFMA16(ahi, bo, ao);
          if (has_lo) {
            v8s alo = ld_a16(&hrow[512 + kk * 32 + quad * 8]);
            ai = MFMA16(alo, bi, ai); af = MFMA16(alo, bf, af);
            ag = MFMA16(alo, bgv, ag); ao = MFMA16(alo, bo, ao);
          }
        }
      }
      if (t > 0) { // hl(t-1): parity (t-1)&1, weight K offset 512
        const ushort* hrow = hlb + ((t - 1) & 1) * slotE + (b0 + mrow) * hstride;
#pragma unroll 4
        for (int kk = 0; kk < 16; ++kk) {
          v8s ahi = ld_a16(&hrow[kk * 32 + quad * 8]);
          v8s bi = *(const v8s*)&smemU[(r16) * 1032 + 512 + kk * 32 + quad * 8];
          v8s bf = *(const v8s*)&smemU[(16 + r16) * 1032 + 512 + kk * 32 + quad * 8];
          v8s bgv = *(const v8s*)&smemU[(32 + r16) * 1032 + 512 + kk * 32 + quad * 8];
          v8s bo = *(const v8s*)&smemU[(48 + r16) * 1032 + 512 + kk * 32 + quad * 8];
          ai = MFMA16(ahi, bi, ai); af = MFMA16(ahi, bf, af);
          ag = MFMA16(ahi, bgv, ag); ao = MFMA16(ahi, bo, ao);
          if (has_lo) {
            v8s alo = ld_a16(&hrow[512 + kk * 32 + quad * 8]);
            ai = MFMA16(alo, bi, ai); af = MFMA16(alo, bf, af);
            ag = MFMA16(alo, bgv, ag); ao = MFMA16(alo, bo, ao);
          }
        }
      }

      ushort* hout = hlb + (t & 1) * slotE;
#pragma unroll
      for (int rg = 0; rg < 4; ++rg) {
        float i_ = sigf(ai[rg] + b_i), f_ = sigf(af[rg] + b_f);
        float g_ = tanhf_fast(ag[rg] + b_g), o_ = sigf(ao[rg] + b_o);
        float cn = f_ * creg[rg] + i_ * g_;
        creg[rg] = cn;
        float hv = o_ * tanhf_fast(cn);
        ushort uh = f2us(hv);
        const int rb = (bglob + rg) * hstride;
        st_wt(&hout[rb + col], uh);
        if (has_lo) st_wt(&hout[rb + 512 + col], f2us(hv - us2f(uh)));
      }

      __syncthreads();
      if (tid == 0)
        __hip_atomic_fetch_add(lstm_done + stripe * 64, 1, __ATOMIC_RELAXED, __HIP_MEMORY_SCOPE_AGENT);
    }
  }
}

// out = h_final @ head_w.T + head_b (f32). h_final = hl parity 1 hi(+lo).
__global__ void head_kernel(const char* __restrict__ ws,
                            const float* __restrict__ hw,   // [6][512]
                            const float* __restrict__ hbias,// [6]
                            float* __restrict__ out,        // [128][6]
                            int hstride, int has_lo) {
  const ushort* h1 = (const ushort*)(ws + RING_OFF) + 3 * 128 * hstride;
  const int b = blockIdx.x, l = threadIdx.x;   // 64 threads; lane l owns k=l*8..l*8+7
  const int k0 = l * 8;
  v8s hi = ld_a16(&h1[b * hstride + k0]);
  v8s lo;
  if (has_lo) lo = ld_a16(&h1[b * hstride + 512 + k0]);
  float acc[6] = {0.f, 0.f, 0.f, 0.f, 0.f, 0.f};
#pragma unroll
  for (int j = 0; j < 8; ++j) {
    float h = us2f((ushort)hi[j]);
    if (has_lo) h += us2f((ushort)lo[j]);
#pragma unroll
    for (int o = 0; o < 6; ++o) acc[o] += h * hw[o * 512 + k0 + j];
  }
#pragma unroll
  for (int o = 0; o < 6; ++o) {
    float v = acc[o];
    for (int off = 32; off > 0; off >>= 1) v += __shfl_down(v, off);
    if (l == 0) out[b * 6 + o] = v + hbias[o];
  }
}

// zero the counter region with write-through stores (no cached ws lines)
__global__ void init_ws(int* cnt) {
  int i = blockIdx.x * blockDim.x + threadIdx.x;
  if (i < 2048)
    __hip_atomic_store(cnt + i, 0, __ATOMIC_RELAXED, __HIP_MEMORY_SCOPE_AGENT);
}

__global__ void ws_too_small_marker(float* out) {
  if (threadIdx.x == 0 && blockIdx.x == 0) out[0] = 12345.0f;
}

extern "C" void kernel_launch(void* const* d_in, const int* in_sizes, int n_in,
                              void* d_out, int out_size, void* d_ws, size_t ws_size,
                              hipStream_t stream) {
  const int*   tok  = (const int*)d_in[0];
  const float* emb  = (const float*)d_in[1];
  const float* gwih = (const float*)d_in[2];
  const float* gwhh = (const float*)d_in[3];
  const float* gb   = (const float*)d_in[4];
  const float* gbn  = (const float*)d_in[5];
  const float* lwih = (const float*)d_in[6];
  const float* lwhh = (const float*)d_in[7];
  const float* lb   = (const float*)d_in[8];
  const float* hw   = (const float*)d_in[9];
  const float* hb   = (const float*)d_in[10];

  (void)in_sizes; (void)n_in; (void)out_size;

  const size_t WS_A = (size_t)RING_OFF + 4ull * 128 * 1024 * 2;  // 1,056,768
  const size_t WS_B = (size_t)RING_OFF + 4ull * 128 * 512 * 2;   //   532,480
  if (ws_size < WS_B) {
    hipLaunchKernelGGL(ws_too_small_marker, dim3(1), dim3(64), 0, stream, (float*)d_out);
    return;
  }
  const int has_lo  = (ws_size >= (size_t)WS_A) ? 1 : 0;
  const int hstride = has_lo ? 1024 : 512;

  (void)hipFuncSetAttribute(reinterpret_cast<const void*>(rnn_persistent),
                            hipFuncAttributeMaxDynamicSharedMemorySize, DYN_LDS);
  hipLaunchKernelGGL(init_ws, dim3(8), dim3(256), 0, stream, (int*)d_ws);
  hipLaunchKernelGGL(rnn_persistent, dim3(128), dim3(256), DYN_LDS, stream,
                     tok, emb, gwih, gwhh, gb, gbn, lwih, lwhh, lb,
                     (char*)d_ws, hstride, has_lo);
  hipLaunchKernelGGL(head_kernel, dim3(128), dim3(64), 0, stream,
                     (const char*)d_ws, hw, hb, (float*)d_out, hstride, has_lo);
}